// Round 4
// baseline (337.171 us; speedup 1.0000x reference)
//
#include <hip/hip_runtime.h>

#define NB  64
#define ND  128
#define NLC 1024
#define NLQ 256
#define FNEG (-1e30f)

typedef __bf16 bf16x8 __attribute__((ext_vector_type(8)));
typedef float f32x4 __attribute__((ext_vector_type(4)));

__device__ __forceinline__ ushort f2bf(float x) {
  unsigned u = __float_as_uint(x);
  return (ushort)((u + 0x7fffu + ((u >> 16) & 1u)) >> 16);
}
__device__ __forceinline__ float bf2f(ushort u) {
  return __uint_as_float((unsigned)u << 16);
}
__device__ __forceinline__ bf16x8 ldfrag(const ushort* p) {
  return *reinterpret_cast<const bf16x8*>(p);
}
__device__ __forceinline__ uint4 pack8(float a0, float a1, float a2, float a3,
                                       float a4, float a5, float a6, float a7) {
  uint4 pk;
  pk.x = (unsigned)f2bf(a0) | ((unsigned)f2bf(a1) << 16);
  pk.y = (unsigned)f2bf(a2) | ((unsigned)f2bf(a3) << 16);
  pk.z = (unsigned)f2bf(a4) | ((unsigned)f2bf(a5) << 16);
  pk.w = (unsigned)f2bf(a6) | ((unsigned)f2bf(a7) << 16);
  return pk;
}

// -------------------------------------------------------------------------
// Ctw3[b][l][d]=bf16(C*w3) (transpose), Qt16[b][m][d]=bf16(Q) (transpose),
// Cn16[b][d][l]=bf16(C) (pack), Qn16[b][d][m]=bf16(Q) (pack)
// FUSED: c1part[half][b][l] = sum_{d in half} C[d][l]*w1[d]
//        q2part[half][b][m] = sum_{d in half} Q[d][m]*w2[d]
__global__ __launch_bounds__(256) void convert_kernel(
    const float* __restrict__ C, const float* __restrict__ Q,
    const float* __restrict__ w,
    ushort* __restrict__ Ctw3, ushort* __restrict__ Qt16,
    ushort* __restrict__ Cn16, ushort* __restrict__ Qn16,
    float* __restrict__ c1part, float* __restrict__ q2part) {
  __shared__ float tile[64][65];
  __shared__ float cred[64][4];
  int b = blockIdx.y;
  int tid = blockIdx.x;
  int t = threadIdx.x, c = t & 63, r0 = t >> 6;
  if (tid < 32) {
    int d0 = (tid >> 4) * 64, l0 = (tid & 15) * 64;
    const float* src = C + (size_t)b * ND * NLC;
    float part = 0.f;
#pragma unroll
    for (int p = 0; p < 16; ++p) {
      int r = r0 + p * 4;
      float v = src[(size_t)(d0 + r) * NLC + l0 + c];
      tile[c][r] = v * w[2 * ND + d0 + r];
      part += v * w[d0 + r];
    }
    cred[c][r0] = part;
    __syncthreads();
    ushort* dst = Ctw3 + (size_t)b * NLC * ND;
#pragma unroll
    for (int p = 0; p < 16; ++p) {
      int r = r0 + p * 4;
      dst[(size_t)(l0 + r) * ND + d0 + c] = f2bf(tile[r][c]);
    }
    if (t < 64)
      c1part[(size_t)(tid >> 4) * NB * NLC + b * NLC + l0 + t] =
          cred[t][0] + cred[t][1] + cred[t][2] + cred[t][3];
  } else if (tid < 40) {
    int q = tid - 32;
    int d0 = (q >> 2) * 64, m0 = (q & 3) * 64;
    const float* src = Q + (size_t)b * ND * NLQ;
    float part = 0.f;
#pragma unroll
    for (int p = 0; p < 16; ++p) {
      int r = r0 + p * 4;
      float v = src[(size_t)(d0 + r) * NLQ + m0 + c];
      tile[c][r] = v;
      part += v * w[ND + d0 + r];
    }
    cred[c][r0] = part;
    __syncthreads();
    ushort* dst = Qt16 + (size_t)b * NLQ * ND;
#pragma unroll
    for (int p = 0; p < 16; ++p) {
      int r = r0 + p * 4;
      dst[(size_t)(m0 + r) * ND + d0 + c] = f2bf(tile[r][c]);
    }
    if (t < 64)
      q2part[(size_t)(q >> 2) * NB * NLQ + b * NLQ + m0 + t] =
          cred[t][0] + cred[t][1] + cred[t][2] + cred[t][3];
  } else if (tid < 56) {
    // Cn16 straight pack: 16 blocks x 8192 elems
    size_t ofs = (size_t)(tid - 40) * 8192;
    const float* src = C + (size_t)b * ND * NLC + ofs;
    ushort* dst = Cn16 + (size_t)b * ND * NLC + ofs;
#pragma unroll
    for (int it = 0; it < 4; ++it) {
      int e = (it * 256 + t) * 8;
      float4 v0 = *(const float4*)(src + e), v1 = *(const float4*)(src + e + 4);
      *(uint4*)(dst + e) = pack8(v0.x, v0.y, v0.z, v0.w, v1.x, v1.y, v1.z, v1.w);
    }
  } else {
    // Qn16 straight pack: 2 blocks x 16384 elems
    size_t ofs = (size_t)(tid - 56) * 16384;
    const float* src = Q + (size_t)b * ND * NLQ + ofs;
    ushort* dst = Qn16 + (size_t)b * ND * NLQ + ofs;
#pragma unroll
    for (int it = 0; it < 8; ++it) {
      int e = (it * 256 + t) * 8;
      float4 v0 = *(const float4*)(src + e), v1 = *(const float4*)(src + e + 4);
      *(uint4*)(dst + e) = pack8(v0.x, v0.y, v0.z, v0.w, v1.x, v1.y, v1.z, v1.w);
    }
  }
}

// -------------------------------------------------------------------------
// Fused: S-tile (128 l x 256 m, K=128 MFMA) + biases; row max/sum; e1=bf16
// exp(S+qneg-rmax); column partial sums; e1g store; AND the per-chunk
// partial T GEMM:
//   Tpart[b][chunk][d][m] = sum_{l in chunk} Cn16[d][l] * (e1[l][m]*rowfac[l])
// B operand (bounce2[m][l]) LDS-resident; A fragments read direct from global
// (Cn16 is L2-resident, 256KB/batch). LDS kept <74KB -> 2 blocks/CU.
__global__ __launch_bounds__(512, 4) void score_stats(
    const ushort* __restrict__ Ctw3, const ushort* __restrict__ Qt16,
    const ushort* __restrict__ Cn16,
    const float* __restrict__ c1part, const float* __restrict__ q2part,
    const float* __restrict__ cmask, const float* __restrict__ qmask,
    ushort* __restrict__ e1g, float* __restrict__ rscale_g,
    float* __restrict__ psum_part, float* __restrict__ chunkmax_g,
    float* __restrict__ Tpart) {
  __shared__ union {
    struct { __align__(16) ushort As[128 * 32]; __align__(16) ushort Bs[256 * 32]; } s;
    struct { float rowred[128][4]; float rowsum[128][4]; float colred[256][2]; } red;
    __align__(16) ushort bounce[128 * 264];
    __align__(16) ushort bounce2[256 * 136];
  } u;
  __shared__ float rmaxs[128];
  __shared__ float rcs[128];   // rmax+cneg, then rowfac
  __shared__ float cnegs[128];
  __shared__ float qnegs[256];
  __shared__ float c1s[128];
  __shared__ float q2s[256];
  __shared__ float chunkmax_s;

  int b = blockIdx.y, chunk = blockIdx.x, l0 = chunk * 128;
  int t = threadIdx.x, lane = t & 63, wid = t >> 6;
  int wy = wid >> 2, wx = wid & 3, ln = lane & 15, qd = lane >> 4;

  if (t < 128) {
    int idx = b * NLC + l0 + t;
    c1s[t] = c1part[idx] + c1part[NB * NLC + idx];
    cnegs[t] = (1.f - cmask[idx]) * FNEG;
  } else if (t < 384) {
    int m = t - 128;
    int idx = b * NLQ + m;
    q2s[m] = q2part[idx] + q2part[NB * NLQ + idx];
    qnegs[m] = (1.f - qmask[idx]) * FNEG;
  }

  const ushort* Ab = Ctw3 + (size_t)b * NLC * ND;
  const ushort* Bb = Qt16 + (size_t)b * NLQ * ND;
  f32x4 acc[4][4];
#pragma unroll
  for (int i = 0; i < 4; ++i)
#pragma unroll
    for (int j = 0; j < 4; ++j) acc[i][j] = (f32x4){0.f, 0.f, 0.f, 0.f};

  // register-prefetched staging: load kk's tiles into regs, write to LDS at
  // loop top, issue kk+1's loads before the MFMA cluster.
  int4 va[3];
  {
#pragma unroll
    for (int p = 0; p < 3; ++p) {
      int e4 = p * 512 + t;
      if (e4 < 512) {
        int r = e4 >> 2, cc = (e4 & 3) * 8;
        va[p] = *(const int4*)(Ab + (size_t)(l0 + r) * ND + 0 + cc);
      } else {
        int e = e4 - 512;
        int r = e >> 2, cc = (e & 3) * 8;
        va[p] = *(const int4*)(Bb + (size_t)r * ND + 0 + cc);
      }
    }
  }
  for (int kk = 0; kk < ND; kk += 32) {
    __syncthreads();  // previous iter's ds_reads done (no-op first iter)
#pragma unroll
    for (int p = 0; p < 3; ++p) {
      int e4 = p * 512 + t;
      if (e4 < 512) {
        int r = e4 >> 2, cc = (e4 & 3) * 8;
        *(int4*)(u.s.As + r * 32 + cc) = va[p];
      } else {
        int e = e4 - 512;
        int r = e >> 2, cc = (e & 3) * 8;
        *(int4*)(u.s.Bs + r * 32 + cc) = va[p];
      }
    }
    __syncthreads();
    if (kk + 32 < ND) {
#pragma unroll
      for (int p = 0; p < 3; ++p) {
        int e4 = p * 512 + t;
        if (e4 < 512) {
          int r = e4 >> 2, cc = (e4 & 3) * 8;
          va[p] = *(const int4*)(Ab + (size_t)(l0 + r) * ND + kk + 32 + cc);
        } else {
          int e = e4 - 512;
          int r = e >> 2, cc = (e & 3) * 8;
          va[p] = *(const int4*)(Bb + (size_t)r * ND + kk + 32 + cc);
        }
      }
    }
    bf16x8 af[4], bfr[4];
#pragma unroll
    for (int i = 0; i < 4; ++i) {
      af[i]  = ldfrag(u.s.As + (wy * 64 + i * 16 + ln) * 32 + qd * 8);
      bfr[i] = ldfrag(u.s.Bs + (wx * 64 + i * 16 + ln) * 32 + qd * 8);
    }
#pragma unroll
    for (int i = 0; i < 4; ++i)
#pragma unroll
      for (int j = 0; j < 4; ++j)
        acc[i][j] = __builtin_amdgcn_mfma_f32_16x16x32_bf16(af[i], bfr[j], acc[i][j], 0, 0, 0);
  }
  __syncthreads();  // all ds_reads of u.s done before u.red writes

  // add biases; qneg per column
  float qnj[4], q2j[4];
#pragma unroll
  for (int j = 0; j < 4; ++j) {
    int m = wx * 64 + j * 16 + ln;
    qnj[j] = qnegs[m];
    q2j[j] = q2s[m];
  }
#pragma unroll
  for (int i = 0; i < 4; ++i)
#pragma unroll
    for (int r = 0; r < 4; ++r) {
      int ll = wy * 64 + i * 16 + qd * 4 + r;
      float cv = c1s[ll];
#pragma unroll
      for (int j = 0; j < 4; ++j) acc[i][j][r] += cv + q2j[j];
    }

  // row max over m
#pragma unroll
  for (int i = 0; i < 4; ++i)
#pragma unroll
    for (int r = 0; r < 4; ++r) {
      float v = -INFINITY;
#pragma unroll
      for (int j = 0; j < 4; ++j) v = fmaxf(v, acc[i][j][r] + qnj[j]);
      v = fmaxf(v, __shfl_xor(v, 1));
      v = fmaxf(v, __shfl_xor(v, 2));
      v = fmaxf(v, __shfl_xor(v, 4));
      v = fmaxf(v, __shfl_xor(v, 8));
      if (ln == 0) u.red.rowred[wy * 64 + i * 16 + qd * 4 + r][wx] = v;
    }
  __syncthreads();
  if (t < 128) {
    float v = fmaxf(fmaxf(u.red.rowred[t][0], u.red.rowred[t][1]),
                    fmaxf(u.red.rowred[t][2], u.red.rowred[t][3]));
    rmaxs[t] = v;
    rcs[t] = v + cnegs[t];
  }
  __syncthreads();
  if (t < 64) {
    float v = fmaxf(rcs[t], rcs[t + 64]);
    v = fmaxf(v, __shfl_xor(v, 1));
    v = fmaxf(v, __shfl_xor(v, 2));
    v = fmaxf(v, __shfl_xor(v, 4));
    v = fmaxf(v, __shfl_xor(v, 8));
    v = fmaxf(v, __shfl_xor(v, 16));
    v = fmaxf(v, __shfl_xor(v, 32));
    if (t == 0) chunkmax_s = v;
  }
  __syncthreads();
  if (t < 128) rcs[t] = __expf(rcs[t] - chunkmax_s);  // rowfac
  __syncthreads();

  // e1 (overwrite acc), row sums, column partial sums
  float cs[4] = {0.f, 0.f, 0.f, 0.f};
#pragma unroll
  for (int i = 0; i < 4; ++i)
#pragma unroll
    for (int r = 0; r < 4; ++r) {
      int ll = wy * 64 + i * 16 + qd * 4 + r;
      float rmx = rmaxs[ll], rf = rcs[ll];
      float rs = 0.f;
#pragma unroll
      for (int j = 0; j < 4; ++j) {
        float e = __expf(acc[i][j][r] + qnj[j] - rmx);
        acc[i][j][r] = e;
        rs += e;
        cs[j] += e * rf;
      }
      rs += __shfl_xor(rs, 1);
      rs += __shfl_xor(rs, 2);
      rs += __shfl_xor(rs, 4);
      rs += __shfl_xor(rs, 8);
      if (ln == 0) u.red.rowsum[ll][wx] = rs;
    }
#pragma unroll
  for (int j = 0; j < 4; ++j) {
    float v = cs[j];
    v += __shfl_xor(v, 16);
    v += __shfl_xor(v, 32);
    if (qd == 0) u.red.colred[wx * 64 + j * 16 + ln][wy] = v;
  }
  __syncthreads();
  if (t < 128)
    rscale_g[b * NLC + l0 + t] = 1.f / (u.red.rowsum[t][0] + u.red.rowsum[t][1] +
                                        u.red.rowsum[t][2] + u.red.rowsum[t][3]);
  if (t >= 256 && t < 512) {
    int m = t - 256;
    psum_part[(b * 8 + chunk) * NLQ + m] = u.red.colred[m][0] + u.red.colred[m][1];
  }
  if (t == 0) chunkmax_g[b * 8 + chunk] = chunkmax_s;
  __syncthreads();  // red reads done before bounce writes

  // pass 1: bounce e1 through LDS for coalesced bf16 stores ([l][m])
#pragma unroll
  for (int i = 0; i < 4; ++i)
#pragma unroll
    for (int r = 0; r < 4; ++r) {
      int ll = wy * 64 + i * 16 + qd * 4 + r;
#pragma unroll
      for (int j = 0; j < 4; ++j)
        u.bounce[ll * 264 + wx * 64 + j * 16 + ln] = f2bf(acc[i][j][r]);
    }
  __syncthreads();
  ushort* Eb = e1g + (size_t)b * NLC * NLQ;
#pragma unroll
  for (int p = 0; p < 8; ++p) {
    int idx4 = p * 512 + t;
    int r = idx4 >> 5, c = (idx4 & 31) * 8;
    *(int4*)(Eb + (size_t)(l0 + r) * NLQ + c) = *(const int4*)(u.bounce + r * 264 + c);
  }
  __syncthreads();

  // ---- fused partial-T phase ----
  // bounce2[m][l] = e1 * rowfac (K=l contiguous); A fragments direct-global.
#pragma unroll
  for (int i = 0; i < 4; ++i)
#pragma unroll
    for (int r = 0; r < 4; ++r) {
      int ll = wy * 64 + i * 16 + qd * 4 + r;
      float rf = rcs[ll];
#pragma unroll
      for (int j = 0; j < 4; ++j)
        u.bounce2[(wx * 64 + j * 16 + ln) * 136 + ll] = f2bf(acc[i][j][r] * rf);
    }
  __syncthreads();
  const ushort* Cb = Cn16 + (size_t)b * ND * NLC;
  f32x4 acc2[4][4];
#pragma unroll
  for (int i = 0; i < 4; ++i)
#pragma unroll
    for (int j = 0; j < 4; ++j) acc2[i][j] = (f32x4){0.f, 0.f, 0.f, 0.f};
#pragma unroll
  for (int kk = 0; kk < 4; ++kk) {
    bf16x8 af2[4], bf2[4];
#pragma unroll
    for (int i = 0; i < 4; ++i)
      af2[i] = ldfrag(Cb + (size_t)(wy * 64 + i * 16 + ln) * NLC + l0 + kk * 32 + qd * 8);
#pragma unroll
    for (int j = 0; j < 4; ++j)
      bf2[j] = ldfrag(u.bounce2 + (wx * 64 + j * 16 + ln) * 136 + kk * 32 + qd * 8);
#pragma unroll
    for (int i = 0; i < 4; ++i)
#pragma unroll
      for (int j = 0; j < 4; ++j)
        acc2[i][j] = __builtin_amdgcn_mfma_f32_16x16x32_bf16(af2[i], bf2[j], acc2[i][j], 0, 0, 0);
  }
  float* Tb = Tpart + (size_t)(b * 8 + chunk) * ND * NLQ;
#pragma unroll
  for (int i = 0; i < 4; ++i)
#pragma unroll
    for (int r = 0; r < 4; ++r) {
      int d = wy * 64 + i * 16 + qd * 4 + r;
#pragma unroll
      for (int j = 0; j < 4; ++j) {
        int m = wx * 64 + j * 16 + ln;
        Tb[(size_t)d * NLQ + m] = acc2[i][j][r];
      }
    }
}

// -------------------------------------------------------------------------
__global__ __launch_bounds__(256) void stat_combine(
    const float* __restrict__ psum_part, const float* __restrict__ chunkmax_g,
    float* __restrict__ cinv) {
  __shared__ float cm[8];
  int b = blockIdx.x, t = threadIdx.x;
  if (t < 8) cm[t] = chunkmax_g[b * 8 + t];
  __syncthreads();
  float K = cm[0];
#pragma unroll
  for (int c = 1; c < 8; ++c) K = fmaxf(K, cm[c]);
  float s = 0.f;
#pragma unroll
  for (int c = 0; c < 8; ++c)
    s += psum_part[(b * 8 + c) * NLQ + t] * __expf(cm[c] - K);
  cinv[b * NLQ + t] = 1.f / s;
}

// -------------------------------------------------------------------------
// Tt[d][m] = bf16( cinv[m] * sum_c exp(cm[c]-K) * Tpart[c][d][m] )
__global__ __launch_bounds__(256) void tcombine(
    const float* __restrict__ Tpart, const float* __restrict__ cinv,
    const float* __restrict__ chunkmax_g, ushort* __restrict__ Tt) {
  int gid = blockIdx.x * 256 + threadIdx.x;
  int e = gid * 4;
  int b = e >> 15;
  int r = e & 32767;
  int m = r & 255;
  const float* cmb = chunkmax_g + b * 8;
  float K = cmb[0];
#pragma unroll
  for (int c = 1; c < 8; ++c) K = fmaxf(K, cmb[c]);
  float4 s = {0.f, 0.f, 0.f, 0.f};
#pragma unroll
  for (int c = 0; c < 8; ++c) {
    float fac = __expf(cmb[c] - K);
    float4 v = *(const float4*)(Tpart + ((size_t)(b * 8 + c)) * ND * NLQ + r);
    s.x += fac * v.x; s.y += fac * v.y; s.z += fac * v.z; s.w += fac * v.w;
  }
  float4 ci = *(const float4*)(cinv + b * NLQ + m);
  ushort4 o;
  o.x = f2bf(s.x * ci.x); o.y = f2bf(s.y * ci.y);
  o.z = f2bf(s.z * ci.z); o.w = f2bf(s.w * ci.w);
  *(ushort4*)(Tt + (size_t)b * ND * NLQ + r) = o;
}

// -------------------------------------------------------------------------
// A[d][l] = sum_m Qn16[d][m]*e1[l][m]; Bv[d][l] = sum_m Tt[d][m]*e1[l][m];
// scale by rscale[l]; write all 4 output channel groups.
// 256 threads, l-tile 128, 2 blocks/CU, register-prefetched staging.
__global__ __launch_bounds__(256, 2) void outk(
    const float* __restrict__ C, const ushort* __restrict__ Qn16,
    const ushort* __restrict__ Tt, const ushort* __restrict__ e1g,
    const float* __restrict__ rscale, float* __restrict__ out) {
  __shared__ __align__(16) ushort As1[128 * 32];
  __shared__ __align__(16) ushort As2[128 * 32];
  __shared__ __align__(16) ushort Bs[128 * 32];
  int b = blockIdx.y;
  int l0 = blockIdx.x * 128;
  const ushort* Qb = Qn16 + (size_t)b * ND * NLQ;
  const ushort* Tb = Tt + (size_t)b * ND * NLQ;
  const ushort* Eb = e1g + (size_t)b * NLC * NLQ;
  int t = threadIdx.x, lane = t & 63, wid = t >> 6, wy = wid >> 1, wx = wid & 1;
  int ln = lane & 15, qd = lane >> 4;
  f32x4 acc1[4][4], acc2[4][4];
#pragma unroll
  for (int i = 0; i < 4; ++i)
#pragma unroll
    for (int j = 0; j < 4; ++j) {
      acc1[i][j] = (f32x4){0.f, 0.f, 0.f, 0.f};
      acc2[i][j] = (f32x4){0.f, 0.f, 0.f, 0.f};
    }

  int4 v1[2], v2[2], v3[2];
#pragma unroll
  for (int p = 0; p < 2; ++p) {
    int e = t * 8 + p * 2048;
    int r = e >> 5, cc = e & 31;
    v1[p] = *(const int4*)(Qb + (size_t)r * NLQ + cc);
    v2[p] = *(const int4*)(Tb + (size_t)r * NLQ + cc);
    v3[p] = *(const int4*)(Eb + (size_t)(l0 + r) * NLQ + cc);
  }
  for (int m0 = 0; m0 < NLQ; m0 += 32) {
    __syncthreads();  // previous iter's ds_reads done
#pragma unroll
    for (int p = 0; p < 2; ++p) {
      int e = t * 8 + p * 2048;
      *(int4*)(As1 + e) = v1[p];
      *(int4*)(As2 + e) = v2[p];
      *(int4*)(Bs + e)  = v3[p];
    }
    __syncthreads();
    if (m0 + 32 < NLQ) {
#pragma unroll
      for (int p = 0; p < 2; ++p) {
        int e = t * 8 + p * 2048;
        int r = e >> 5, cc = e & 31;
        v1[p] = *(const int4*)(Qb + (size_t)r * NLQ + m0 + 32 + cc);
        v2[p] = *(const int4*)(Tb + (size_t)r * NLQ + m0 + 32 + cc);
        v3[p] = *(const int4*)(Eb + (size_t)(l0 + r) * NLQ + m0 + 32 + cc);
      }
    }
    bf16x8 a1[4], a2[4], bfr[4];
#pragma unroll
    for (int i = 0; i < 4; ++i) {
      a1[i] = ldfrag(As1 + (wy * 64 + i * 16 + ln) * 32 + qd * 8);
      a2[i] = ldfrag(As2 + (wy * 64 + i * 16 + ln) * 32 + qd * 8);
      bfr[i] = ldfrag(Bs + (wx * 64 + i * 16 + ln) * 32 + qd * 8);
    }
#pragma unroll
    for (int i = 0; i < 4; ++i)
#pragma unroll
      for (int j = 0; j < 4; ++j) {
        acc1[i][j] = __builtin_amdgcn_mfma_f32_16x16x32_bf16(a1[i], bfr[j], acc1[i][j], 0, 0, 0);
        acc2[i][j] = __builtin_amdgcn_mfma_f32_16x16x32_bf16(a2[i], bfr[j], acc2[i][j], 0, 0, 0);
      }
  }

  const float* Cb = C + (size_t)b * ND * NLC;
  float* outb = out + (size_t)b * 4 * ND * NLC;
#pragma unroll
  for (int j = 0; j < 4; ++j) {
    int l = l0 + wx * 64 + j * 16 + ln;
    float rs = rscale[b * NLC + l];
#pragma unroll
    for (int i = 0; i < 4; ++i)
#pragma unroll
      for (int r = 0; r < 4; ++r) {
        int d = wy * 64 + i * 16 + qd * 4 + r;
        float a = acc1[i][j][r] * rs;
        float bv = acc2[i][j][r] * rs;
        float c = Cb[(size_t)d * NLC + l];
        outb[(size_t)d * NLC + l] = c;
        outb[(size_t)(128 + d) * NLC + l] = a;
        outb[(size_t)(256 + d) * NLC + l] = c * a;
        outb[(size_t)(384 + d) * NLC + l] = c * bv;
      }
  }
}

// -------------------------------------------------------------------------
extern "C" void kernel_launch(void* const* d_in, const int* in_sizes, int n_in,
                              void* d_out, int out_size, void* d_ws, size_t ws_size,
                              hipStream_t stream) {
  const float* C     = (const float*)d_in[0];
  const float* Q     = (const float*)d_in[1];
  const float* cmask = (const float*)d_in[2];
  const float* qmask = (const float*)d_in[3];
  const float* w     = (const float*)d_in[4];
  float* out = (float*)d_out;

  char* p = (char*)d_ws;
  auto alloc = [&](size_t bytes) { char* r = p; p += (bytes + 255) & ~(size_t)255; return r; };
  ushort* e1g    = (ushort*)alloc((size_t)NB * NLC * NLQ * 2);
  ushort* Ctw3   = (ushort*)alloc((size_t)NB * NLC * ND * 2);
  ushort* Qt16   = (ushort*)alloc((size_t)NB * NLQ * ND * 2);
  ushort* Cn16   = (ushort*)alloc((size_t)NB * ND * NLC * 2);
  ushort* Qn16   = (ushort*)alloc((size_t)NB * ND * NLQ * 2);
  float*  Tpart  = (float*)alloc((size_t)NB * 8 * ND * NLQ * 4);
  ushort* Tt     = (ushort*)alloc((size_t)NB * ND * NLQ * 2);
  float*  c1part = (float*)alloc((size_t)2 * NB * NLC * 4);
  float*  q2part = (float*)alloc((size_t)2 * NB * NLQ * 4);
  float*  rscale = (float*)alloc((size_t)NB * NLC * 4);
  float*  cinv   = (float*)alloc((size_t)NB * NLQ * 4);
  float*  psum   = (float*)alloc((size_t)NB * 8 * NLQ * 4);
  float*  chmax  = (float*)alloc((size_t)NB * 8 * 4);

  convert_kernel<<<dim3(58, NB), 256, 0, stream>>>(C, Q, w, Ctw3, Qt16, Cn16, Qn16,
                                                   c1part, q2part);
  score_stats<<<dim3(NLC / 128, NB), 512, 0, stream>>>(
      Ctw3, Qt16, Cn16, c1part, q2part, cmask, qmask, e1g, rscale, psum, chmax, Tpart);
  stat_combine<<<NB, 256, 0, stream>>>(psum, chmax, cinv);
  tcombine<<<(NB * ND * NLQ / 4) / 256, 256, 0, stream>>>(Tpart, cinv, chmax, Tt);
  outk<<<dim3(NLC / 128, NB), 256, 0, stream>>>(C, Qn16, Tt, e1g, rscale, out);
}

// Round 5
// 267.075 us; speedup vs baseline: 1.2625x; 1.2625x over previous
//
#include <hip/hip_runtime.h>

#define NB  64
#define ND  128
#define NLC 1024
#define NLQ 256
#define FNEG (-1e30f)

typedef __bf16 bf16x8 __attribute__((ext_vector_type(8)));
typedef float f32x4 __attribute__((ext_vector_type(4)));

__device__ __forceinline__ ushort f2bf(float x) {
  unsigned u = __float_as_uint(x);
  return (ushort)((u + 0x7fffu + ((u >> 16) & 1u)) >> 16);
}
__device__ __forceinline__ float bf2f(ushort u) {
  return __uint_as_float((unsigned)u << 16);
}
__device__ __forceinline__ bf16x8 ldfrag(const ushort* p) {
  return *reinterpret_cast<const bf16x8*>(p);
}
__device__ __forceinline__ uint4 pack8(float a0, float a1, float a2, float a3,
                                       float a4, float a5, float a6, float a7) {
  uint4 pk;
  pk.x = (unsigned)f2bf(a0) | ((unsigned)f2bf(a1) << 16);
  pk.y = (unsigned)f2bf(a2) | ((unsigned)f2bf(a3) << 16);
  pk.z = (unsigned)f2bf(a4) | ((unsigned)f2bf(a5) << 16);
  pk.w = (unsigned)f2bf(a6) | ((unsigned)f2bf(a7) << 16);
  return pk;
}

// -------------------------------------------------------------------------
// Ctw3[b][l][d]=bf16(C*w3) (transpose), Qt16[b][m][d]=bf16(Q) (transpose),
// Cn16[b][d][l]=bf16(C) (pack), Qn16[b][d][m]=bf16(Q) (pack)
// FUSED: c1part/q2part partial bias dots, AND out channel-0 = C (f32 copy).
__global__ __launch_bounds__(256) void convert_kernel(
    const float* __restrict__ C, const float* __restrict__ Q,
    const float* __restrict__ w,
    ushort* __restrict__ Ctw3, ushort* __restrict__ Qt16,
    ushort* __restrict__ Cn16, ushort* __restrict__ Qn16,
    float* __restrict__ c1part, float* __restrict__ q2part,
    float* __restrict__ out) {
  __shared__ float tile[64][65];
  __shared__ float cred[64][4];
  int b = blockIdx.y;
  int tid = blockIdx.x;
  int t = threadIdx.x, c = t & 63, r0 = t >> 6;
  if (tid < 32) {
    int d0 = (tid >> 4) * 64, l0 = (tid & 15) * 64;
    const float* src = C + (size_t)b * ND * NLC;
    float* o0 = out + (size_t)b * 4 * ND * NLC;
    float part = 0.f;
#pragma unroll
    for (int p = 0; p < 16; ++p) {
      int r = r0 + p * 4;
      float v = src[(size_t)(d0 + r) * NLC + l0 + c];
      tile[c][r] = v * w[2 * ND + d0 + r];
      part += v * w[d0 + r];
      o0[(size_t)(d0 + r) * NLC + l0 + c] = v;   // channel 0 = C copy
    }
    cred[c][r0] = part;
    __syncthreads();
    ushort* dst = Ctw3 + (size_t)b * NLC * ND;
#pragma unroll
    for (int p = 0; p < 16; ++p) {
      int r = r0 + p * 4;
      dst[(size_t)(l0 + r) * ND + d0 + c] = f2bf(tile[r][c]);
    }
    if (t < 64)
      c1part[(size_t)(tid >> 4) * NB * NLC + b * NLC + l0 + t] =
          cred[t][0] + cred[t][1] + cred[t][2] + cred[t][3];
  } else if (tid < 40) {
    int q = tid - 32;
    int d0 = (q >> 2) * 64, m0 = (q & 3) * 64;
    const float* src = Q + (size_t)b * ND * NLQ;
    float part = 0.f;
#pragma unroll
    for (int p = 0; p < 16; ++p) {
      int r = r0 + p * 4;
      float v = src[(size_t)(d0 + r) * NLQ + m0 + c];
      tile[c][r] = v;
      part += v * w[ND + d0 + r];
    }
    cred[c][r0] = part;
    __syncthreads();
    ushort* dst = Qt16 + (size_t)b * NLQ * ND;
#pragma unroll
    for (int p = 0; p < 16; ++p) {
      int r = r0 + p * 4;
      dst[(size_t)(m0 + r) * ND + d0 + c] = f2bf(tile[r][c]);
    }
    if (t < 64)
      q2part[(size_t)(q >> 2) * NB * NLQ + b * NLQ + m0 + t] =
          cred[t][0] + cred[t][1] + cred[t][2] + cred[t][3];
  } else if (tid < 56) {
    size_t ofs = (size_t)(tid - 40) * 8192;
    const float* src = C + (size_t)b * ND * NLC + ofs;
    ushort* dst = Cn16 + (size_t)b * ND * NLC + ofs;
#pragma unroll
    for (int it = 0; it < 4; ++it) {
      int e = (it * 256 + t) * 8;
      float4 v0 = *(const float4*)(src + e), v1 = *(const float4*)(src + e + 4);
      *(uint4*)(dst + e) = pack8(v0.x, v0.y, v0.z, v0.w, v1.x, v1.y, v1.z, v1.w);
    }
  } else {
    size_t ofs = (size_t)(tid - 56) * 16384;
    const float* src = Q + (size_t)b * ND * NLQ + ofs;
    ushort* dst = Qn16 + (size_t)b * ND * NLQ + ofs;
#pragma unroll
    for (int it = 0; it < 8; ++it) {
      int e = (it * 256 + t) * 8;
      float4 v0 = *(const float4*)(src + e), v1 = *(const float4*)(src + e + 4);
      *(uint4*)(dst + e) = pack8(v0.x, v0.y, v0.z, v0.w, v1.x, v1.y, v1.z, v1.w);
    }
  }
}

// -------------------------------------------------------------------------
// Fused: S-tile (128 l x 256 m, K=128 MFMA) + biases; row max/sum; e1=bf16;
// column partial sums; e1g store; per-chunk partial T GEMM (B in LDS,
// A fragments direct from L2-resident Cn16). Slim LDS union (~74KB) ->
// 2 blocks/CU with (512,4).
__global__ __launch_bounds__(512, 4) void score_stats(
    const ushort* __restrict__ Ctw3, const ushort* __restrict__ Qt16,
    const ushort* __restrict__ Cn16,
    const float* __restrict__ c1part, const float* __restrict__ q2part,
    const float* __restrict__ cmask, const float* __restrict__ qmask,
    ushort* __restrict__ e1g, float* __restrict__ rscale_g,
    float* __restrict__ psum_part, float* __restrict__ chunkmax_g,
    float* __restrict__ Tpart) {
  __shared__ union {
    struct { __align__(16) ushort As[128 * 32]; __align__(16) ushort Bs[256 * 32]; } s;
    struct { float rowred[128][4]; float rowsum[128][4]; float colred[256][2]; } red;
    __align__(16) ushort bounce[128 * 264];
    __align__(16) ushort bounce2[256 * 136];
  } u;
  __shared__ float rmaxs[128];
  __shared__ float rcs[128];   // rmax+cneg, then rowfac
  __shared__ float cnegs[128];
  __shared__ float qnegs[256];
  __shared__ float c1s[128];
  __shared__ float q2s[256];
  __shared__ float chunkmax_s;

  int b = blockIdx.y, chunk = blockIdx.x, l0 = chunk * 128;
  int t = threadIdx.x, lane = t & 63, wid = t >> 6;
  int wy = wid >> 2, wx = wid & 3, ln = lane & 15, qd = lane >> 4;

  if (t < 128) {
    int idx = b * NLC + l0 + t;
    c1s[t] = c1part[idx] + c1part[NB * NLC + idx];
    cnegs[t] = (1.f - cmask[idx]) * FNEG;
  } else if (t < 384) {
    int m = t - 128;
    int idx = b * NLQ + m;
    q2s[m] = q2part[idx] + q2part[NB * NLQ + idx];
    qnegs[m] = (1.f - qmask[idx]) * FNEG;
  }

  const ushort* Ab = Ctw3 + (size_t)b * NLC * ND;
  const ushort* Bb = Qt16 + (size_t)b * NLQ * ND;
  f32x4 acc[4][4];
#pragma unroll
  for (int i = 0; i < 4; ++i)
#pragma unroll
    for (int j = 0; j < 4; ++j) acc[i][j] = (f32x4){0.f, 0.f, 0.f, 0.f};

  for (int kk = 0; kk < ND; kk += 32) {
#pragma unroll
    for (int p = 0; p < 3; ++p) {
      int e4 = p * 512 + t;
      if (e4 < 512) {
        int r = e4 >> 2, cc = (e4 & 3) * 8;
        *(int4*)(u.s.As + r * 32 + cc) = *(const int4*)(Ab + (size_t)(l0 + r) * ND + kk + cc);
      } else {
        int e = e4 - 512;
        int r = e >> 2, cc = (e & 3) * 8;
        *(int4*)(u.s.Bs + r * 32 + cc) = *(const int4*)(Bb + (size_t)r * ND + kk + cc);
      }
    }
    __syncthreads();
    bf16x8 af[4], bfr[4];
#pragma unroll
    for (int i = 0; i < 4; ++i) {
      af[i]  = ldfrag(u.s.As + (wy * 64 + i * 16 + ln) * 32 + qd * 8);
      bfr[i] = ldfrag(u.s.Bs + (wx * 64 + i * 16 + ln) * 32 + qd * 8);
    }
#pragma unroll
    for (int i = 0; i < 4; ++i)
#pragma unroll
      for (int j = 0; j < 4; ++j)
        acc[i][j] = __builtin_amdgcn_mfma_f32_16x16x32_bf16(af[i], bfr[j], acc[i][j], 0, 0, 0);
    __syncthreads();
  }

  // add biases; qneg per column
  float qnj[4], q2j[4];
#pragma unroll
  for (int j = 0; j < 4; ++j) {
    int m = wx * 64 + j * 16 + ln;
    qnj[j] = qnegs[m];
    q2j[j] = q2s[m];
  }
#pragma unroll
  for (int i = 0; i < 4; ++i)
#pragma unroll
    for (int r = 0; r < 4; ++r) {
      int ll = wy * 64 + i * 16 + qd * 4 + r;
      float cv = c1s[ll];
#pragma unroll
      for (int j = 0; j < 4; ++j) acc[i][j][r] += cv + q2j[j];
    }

  // row max over m
#pragma unroll
  for (int i = 0; i < 4; ++i)
#pragma unroll
    for (int r = 0; r < 4; ++r) {
      float v = -INFINITY;
#pragma unroll
      for (int j = 0; j < 4; ++j) v = fmaxf(v, acc[i][j][r] + qnj[j]);
      v = fmaxf(v, __shfl_xor(v, 1));
      v = fmaxf(v, __shfl_xor(v, 2));
      v = fmaxf(v, __shfl_xor(v, 4));
      v = fmaxf(v, __shfl_xor(v, 8));
      if (ln == 0) u.red.rowred[wy * 64 + i * 16 + qd * 4 + r][wx] = v;
    }
  __syncthreads();
  if (t < 128) {
    float v = fmaxf(fmaxf(u.red.rowred[t][0], u.red.rowred[t][1]),
                    fmaxf(u.red.rowred[t][2], u.red.rowred[t][3]));
    rmaxs[t] = v;
    rcs[t] = v + cnegs[t];
  }
  __syncthreads();
  if (t < 64) {
    float v = fmaxf(rcs[t], rcs[t + 64]);
    v = fmaxf(v, __shfl_xor(v, 1));
    v = fmaxf(v, __shfl_xor(v, 2));
    v = fmaxf(v, __shfl_xor(v, 4));
    v = fmaxf(v, __shfl_xor(v, 8));
    v = fmaxf(v, __shfl_xor(v, 16));
    v = fmaxf(v, __shfl_xor(v, 32));
    if (t == 0) chunkmax_s = v;
  }
  __syncthreads();
  if (t < 128) rcs[t] = __expf(rcs[t] - chunkmax_s);  // rowfac
  __syncthreads();

  // e1 (overwrite acc), row sums, column partial sums
  float cs[4] = {0.f, 0.f, 0.f, 0.f};
#pragma unroll
  for (int i = 0; i < 4; ++i)
#pragma unroll
    for (int r = 0; r < 4; ++r) {
      int ll = wy * 64 + i * 16 + qd * 4 + r;
      float rmx = rmaxs[ll], rf = rcs[ll];
      float rs = 0.f;
#pragma unroll
      for (int j = 0; j < 4; ++j) {
        float e = __expf(acc[i][j][r] + qnj[j] - rmx);
        acc[i][j][r] = e;
        rs += e;
        cs[j] += e * rf;
      }
      rs += __shfl_xor(rs, 1);
      rs += __shfl_xor(rs, 2);
      rs += __shfl_xor(rs, 4);
      rs += __shfl_xor(rs, 8);
      if (ln == 0) u.red.rowsum[ll][wx] = rs;
    }
#pragma unroll
  for (int j = 0; j < 4; ++j) {
    float v = cs[j];
    v += __shfl_xor(v, 16);
    v += __shfl_xor(v, 32);
    if (qd == 0) u.red.colred[wx * 64 + j * 16 + ln][wy] = v;
  }
  __syncthreads();
  if (t < 128)
    rscale_g[b * NLC + l0 + t] = 1.f / (u.red.rowsum[t][0] + u.red.rowsum[t][1] +
                                        u.red.rowsum[t][2] + u.red.rowsum[t][3]);
  if (t >= 256 && t < 512) {
    int m = t - 256;
    psum_part[(b * 8 + chunk) * NLQ + m] = u.red.colred[m][0] + u.red.colred[m][1];
  }
  if (t == 0) chunkmax_g[b * 8 + chunk] = chunkmax_s;
  __syncthreads();  // red reads done before bounce writes

  // pass 1: bounce e1 through LDS for coalesced bf16 stores ([l][m])
#pragma unroll
  for (int i = 0; i < 4; ++i)
#pragma unroll
    for (int r = 0; r < 4; ++r) {
      int ll = wy * 64 + i * 16 + qd * 4 + r;
#pragma unroll
      for (int j = 0; j < 4; ++j)
        u.bounce[ll * 264 + wx * 64 + j * 16 + ln] = f2bf(acc[i][j][r]);
    }
  __syncthreads();
  ushort* Eb = e1g + (size_t)b * NLC * NLQ;
#pragma unroll
  for (int p = 0; p < 8; ++p) {
    int idx4 = p * 512 + t;
    int r = idx4 >> 5, c = (idx4 & 31) * 8;
    *(int4*)(Eb + (size_t)(l0 + r) * NLQ + c) = *(const int4*)(u.bounce + r * 264 + c);
  }
  __syncthreads();

  // ---- fused partial-T phase ----
#pragma unroll
  for (int i = 0; i < 4; ++i)
#pragma unroll
    for (int r = 0; r < 4; ++r) {
      int ll = wy * 64 + i * 16 + qd * 4 + r;
      float rf = rcs[ll];
#pragma unroll
      for (int j = 0; j < 4; ++j)
        u.bounce2[(wx * 64 + j * 16 + ln) * 136 + ll] = f2bf(acc[i][j][r] * rf);
    }
  __syncthreads();
  const ushort* Cb = Cn16 + (size_t)b * ND * NLC;
  f32x4 acc2[4][4];
#pragma unroll
  for (int i = 0; i < 4; ++i)
#pragma unroll
    for (int j = 0; j < 4; ++j) acc2[i][j] = (f32x4){0.f, 0.f, 0.f, 0.f};
#pragma unroll
  for (int kk = 0; kk < 4; ++kk) {
    bf16x8 af2[4], bf2[4];
#pragma unroll
    for (int i = 0; i < 4; ++i)
      af2[i] = ldfrag(Cb + (size_t)(wy * 64 + i * 16 + ln) * NLC + l0 + kk * 32 + qd * 8);
#pragma unroll
    for (int j = 0; j < 4; ++j)
      bf2[j] = ldfrag(u.bounce2 + (wx * 64 + j * 16 + ln) * 136 + kk * 32 + qd * 8);
#pragma unroll
    for (int i = 0; i < 4; ++i)
#pragma unroll
      for (int j = 0; j < 4; ++j)
        acc2[i][j] = __builtin_amdgcn_mfma_f32_16x16x32_bf16(af2[i], bf2[j], acc2[i][j], 0, 0, 0);
  }
  float* Tb = Tpart + (size_t)(b * 8 + chunk) * ND * NLQ;
#pragma unroll
  for (int i = 0; i < 4; ++i)
#pragma unroll
    for (int r = 0; r < 4; ++r) {
      int d = wy * 64 + i * 16 + qd * 4 + r;
#pragma unroll
      for (int j = 0; j < 4; ++j) {
        int m = wx * 64 + j * 16 + ln;
        Tb[(size_t)d * NLQ + m] = acc2[i][j][r];
      }
    }
}

// -------------------------------------------------------------------------
__global__ __launch_bounds__(256) void stat_combine(
    const float* __restrict__ psum_part, const float* __restrict__ chunkmax_g,
    float* __restrict__ cinv) {
  __shared__ float cm[8];
  int b = blockIdx.x, t = threadIdx.x;
  if (t < 8) cm[t] = chunkmax_g[b * 8 + t];
  __syncthreads();
  float K = cm[0];
#pragma unroll
  for (int c = 1; c < 8; ++c) K = fmaxf(K, cm[c]);
  float s = 0.f;
#pragma unroll
  for (int c = 0; c < 8; ++c)
    s += psum_part[(b * 8 + c) * NLQ + t] * __expf(cm[c] - K);
  cinv[b * NLQ + t] = 1.f / s;
}

// -------------------------------------------------------------------------
__global__ __launch_bounds__(256) void tcombine(
    const float* __restrict__ Tpart, const float* __restrict__ cinv,
    const float* __restrict__ chunkmax_g, ushort* __restrict__ Tt) {
  int gid = blockIdx.x * 256 + threadIdx.x;
  int e = gid * 4;
  int b = e >> 15;
  int r = e & 32767;
  int m = r & 255;
  const float* cmb = chunkmax_g + b * 8;
  float K = cmb[0];
#pragma unroll
  for (int c = 1; c < 8; ++c) K = fmaxf(K, cmb[c]);
  float4 s = {0.f, 0.f, 0.f, 0.f};
#pragma unroll
  for (int c = 0; c < 8; ++c) {
    float fac = __expf(cmb[c] - K);
    float4 v = *(const float4*)(Tpart + ((size_t)(b * 8 + c)) * ND * NLQ + r);
    s.x += fac * v.x; s.y += fac * v.y; s.z += fac * v.z; s.w += fac * v.w;
  }
  float4 ci = *(const float4*)(cinv + b * NLQ + m);
  ushort4 o;
  o.x = f2bf(s.x * ci.x); o.y = f2bf(s.y * ci.y);
  o.z = f2bf(s.z * ci.z); o.w = f2bf(s.w * ci.w);
  *(ushort4*)(Tt + (size_t)b * ND * NLQ + r) = o;
}

// -------------------------------------------------------------------------
// A[d][l] = sum_m Qn16[d][m]*e1[l][m]; Bv[d][l] = sum_m Tt[d][m]*e1[l][m];
// 512 threads / 8 waves: wave = (wy d-half 64) x (wx l-quarter 32).
// acc per path = 4x2 f32x4 (64 VGPR both paths) -> fits (512,4) = 2 blk/CU.
// Epilogue: LDS-bounce per 32-d block -> fully coalesced float4 row writes
// of channels {A, C*A, C*Bv} (channel 0 written by convert_kernel).
__global__ __launch_bounds__(512, 4) void outk(
    const float* __restrict__ C, const ushort* __restrict__ Qn16,
    const ushort* __restrict__ Tt, const ushort* __restrict__ e1g,
    const float* __restrict__ rscale, float* __restrict__ out) {
  __shared__ union {
    struct { __align__(16) ushort As1[128 * 32]; __align__(16) ushort As2[128 * 32];
             __align__(16) ushort Bs[128 * 32]; } st;
    struct { float a[32][132]; float bv[32][132]; } ep;
  } u;
  int b = blockIdx.y;
  int l0 = blockIdx.x * 128;
  const ushort* Qb = Qn16 + (size_t)b * ND * NLQ;
  const ushort* Tb = Tt + (size_t)b * ND * NLQ;
  const ushort* Eb = e1g + (size_t)b * NLC * NLQ;
  int t = threadIdx.x, lane = t & 63, wid = t >> 6;
  int wy = wid >> 2, wx = wid & 3;       // wy: d-half, wx: l-quarter
  int ln = lane & 15, qd = lane >> 4;
  f32x4 acc1[4][2], acc2[4][2];
#pragma unroll
  for (int i = 0; i < 4; ++i)
#pragma unroll
    for (int j = 0; j < 2; ++j) {
      acc1[i][j] = (f32x4){0.f, 0.f, 0.f, 0.f};
      acc2[i][j] = (f32x4){0.f, 0.f, 0.f, 0.f};
    }

  for (int m0 = 0; m0 < NLQ; m0 += 32) {
    {
      int r = t >> 2, cc = (t & 3) * 8;
      *(int4*)(u.st.As1 + r * 32 + cc) = *(const int4*)(Qb + (size_t)r * NLQ + m0 + cc);
      *(int4*)(u.st.As2 + r * 32 + cc) = *(const int4*)(Tb + (size_t)r * NLQ + m0 + cc);
      *(int4*)(u.st.Bs + r * 32 + cc)  = *(const int4*)(Eb + (size_t)(l0 + r) * NLQ + m0 + cc);
    }
    __syncthreads();
    bf16x8 a1[4], a2[4], bfr[2];
#pragma unroll
    for (int i = 0; i < 4; ++i) {
      a1[i] = ldfrag(u.st.As1 + (wy * 64 + i * 16 + ln) * 32 + qd * 8);
      a2[i] = ldfrag(u.st.As2 + (wy * 64 + i * 16 + ln) * 32 + qd * 8);
    }
#pragma unroll
    for (int j = 0; j < 2; ++j)
      bfr[j] = ldfrag(u.st.Bs + (wx * 32 + j * 16 + ln) * 32 + qd * 8);
#pragma unroll
    for (int i = 0; i < 4; ++i)
#pragma unroll
      for (int j = 0; j < 2; ++j) {
        acc1[i][j] = __builtin_amdgcn_mfma_f32_16x16x32_bf16(a1[i], bfr[j], acc1[i][j], 0, 0, 0);
        acc2[i][j] = __builtin_amdgcn_mfma_f32_16x16x32_bf16(a2[i], bfr[j], acc2[i][j], 0, 0, 0);
      }
    __syncthreads();
  }

  // rscale per fragment column
  float rsj[2];
#pragma unroll
  for (int j = 0; j < 2; ++j)
    rsj[j] = rscale[b * NLC + l0 + wx * 32 + j * 16 + ln];

  const float* Cbase = C + (size_t)b * ND * NLC;
  float* outb = out + (size_t)b * 4 * ND * NLC;
#pragma unroll
  for (int db = 0; db < 4; ++db) {
    __syncthreads();  // previous pass's LDS reads / staging reads done
    if (wy == (db >> 1)) {
      int ibase = (db & 1) * 2;
#pragma unroll
      for (int ii = 0; ii < 2; ++ii) {
        int i = ibase + ii;
#pragma unroll
        for (int j = 0; j < 2; ++j) {
          int lc = wx * 32 + j * 16 + ln;
#pragma unroll
          for (int r = 0; r < 4; ++r) {
            int dr = ii * 16 + qd * 4 + r;
            u.ep.a[dr][lc]  = acc1[i][j][r] * rsj[j];
            u.ep.bv[dr][lc] = acc2[i][j][r] * rsj[j];
          }
        }
      }
    }
    __syncthreads();
    // coalesced write pass: 32 rows x 128 cols, 16 threads/row x 8 floats
    int row = t >> 4, colf = (t & 15) * 8;
    int d = db * 32 + row;
    const float* Crow = Cbase + (size_t)d * NLC + l0 + colf;
    float4 c0 = *(const float4*)(Crow), c1 = *(const float4*)(Crow + 4);
    float4 a0 = *(const float4*)&u.ep.a[row][colf];
    float4 a1v = *(const float4*)&u.ep.a[row][colf + 4];
    float4 b0 = *(const float4*)&u.ep.bv[row][colf];
    float4 b1 = *(const float4*)&u.ep.bv[row][colf + 4];
    float* oA = outb + (size_t)(128 + d) * NLC + l0 + colf;
    float* oCA = outb + (size_t)(256 + d) * NLC + l0 + colf;
    float* oCB = outb + (size_t)(384 + d) * NLC + l0 + colf;
    *(float4*)(oA) = a0;
    *(float4*)(oA + 4) = a1v;
    *(float4*)(oCA) = (float4){c0.x * a0.x, c0.y * a0.y, c0.z * a0.z, c0.w * a0.w};
    *(float4*)(oCA + 4) = (float4){c1.x * a1v.x, c1.y * a1v.y, c1.z * a1v.z, c1.w * a1v.w};
    *(float4*)(oCB) = (float4){c0.x * b0.x, c0.y * b0.y, c0.z * b0.z, c0.w * b0.w};
    *(float4*)(oCB + 4) = (float4){c1.x * b1.x, c1.y * b1.y, c1.z * b1.z, c1.w * b1.w};
  }
}

// -------------------------------------------------------------------------
extern "C" void kernel_launch(void* const* d_in, const int* in_sizes, int n_in,
                              void* d_out, int out_size, void* d_ws, size_t ws_size,
                              hipStream_t stream) {
  const float* C     = (const float*)d_in[0];
  const float* Q     = (const float*)d_in[1];
  const float* cmask = (const float*)d_in[2];
  const float* qmask = (const float*)d_in[3];
  const float* w     = (const float*)d_in[4];
  float* out = (float*)d_out;

  char* p = (char*)d_ws;
  auto alloc = [&](size_t bytes) { char* r = p; p += (bytes + 255) & ~(size_t)255; return r; };
  ushort* e1g    = (ushort*)alloc((size_t)NB * NLC * NLQ * 2);
  ushort* Ctw3   = (ushort*)alloc((size_t)NB * NLC * ND * 2);
  ushort* Qt16   = (ushort*)alloc((size_t)NB * NLQ * ND * 2);
  ushort* Cn16   = (ushort*)alloc((size_t)NB * ND * NLC * 2);
  ushort* Qn16   = (ushort*)alloc((size_t)NB * ND * NLQ * 2);
  float*  Tpart  = (float*)alloc((size_t)NB * 8 * ND * NLQ * 4);
  ushort* Tt     = (ushort*)alloc((size_t)NB * ND * NLQ * 2);
  float*  c1part = (float*)alloc((size_t)2 * NB * NLC * 4);
  float*  q2part = (float*)alloc((size_t)2 * NB * NLQ * 4);
  float*  rscale = (float*)alloc((size_t)NB * NLC * 4);
  float*  cinv   = (float*)alloc((size_t)NB * NLQ * 4);
  float*  psum   = (float*)alloc((size_t)NB * 8 * NLQ * 4);
  float*  chmax  = (float*)alloc((size_t)NB * 8 * 4);

  convert_kernel<<<dim3(58, NB), 256, 0, stream>>>(C, Q, w, Ctw3, Qt16, Cn16, Qn16,
                                                   c1part, q2part, out);
  score_stats<<<dim3(NLC / 128, NB), 512, 0, stream>>>(
      Ctw3, Qt16, Cn16, c1part, q2part, cmask, qmask, e1g, rscale, psum, chmax, Tpart);
  stat_combine<<<NB, 256, 0, stream>>>(psum, chmax, cinv);
  tcombine<<<(NB * ND * NLQ / 4) / 256, 256, 0, stream>>>(Tpart, cinv, chmax, Tt);
  outk<<<dim3(NLC / 128, NB), 512, 0, stream>>>(C, Qn16, Tt, e1g, rscale, out);
}

// Round 7
// 265.401 us; speedup vs baseline: 1.2704x; 1.0063x over previous
//
#include <hip/hip_runtime.h>

#define NB  64
#define ND  128
#define NLC 1024
#define NLQ 256
#define FNEG (-1e30f)

typedef __bf16 bf16x8 __attribute__((ext_vector_type(8)));
typedef float f32x4 __attribute__((ext_vector_type(4)));

__device__ __forceinline__ ushort f2bf(float x) {
  unsigned u = __float_as_uint(x);
  return (ushort)((u + 0x7fffu + ((u >> 16) & 1u)) >> 16);
}
__device__ __forceinline__ float bf2f(ushort u) {
  return __uint_as_float((unsigned)u << 16);
}
__device__ __forceinline__ bf16x8 ldfrag(const ushort* p) {
  return *reinterpret_cast<const bf16x8*>(p);
}
__device__ __forceinline__ uint4 pack8(float a0, float a1, float a2, float a3,
                                       float a4, float a5, float a6, float a7) {
  uint4 pk;
  pk.x = (unsigned)f2bf(a0) | ((unsigned)f2bf(a1) << 16);
  pk.y = (unsigned)f2bf(a2) | ((unsigned)f2bf(a3) << 16);
  pk.z = (unsigned)f2bf(a4) | ((unsigned)f2bf(a5) << 16);
  pk.w = (unsigned)f2bf(a6) | ((unsigned)f2bf(a7) << 16);
  return pk;
}

// -------------------------------------------------------------------------
// Ctw3[b][l][d]=bf16(C*w3) (transpose), Qt16[b][m][d]=bf16(Q) (transpose),
// Cn16[b][d][l]=bf16(C) (pack), Qn16[b][d][m]=bf16(Q) (pack)
// FUSED: c1part/q2part partial bias dots, AND out channel-0 = C (f32 copy).
__global__ __launch_bounds__(256) void convert_kernel(
    const float* __restrict__ C, const float* __restrict__ Q,
    const float* __restrict__ w,
    ushort* __restrict__ Ctw3, ushort* __restrict__ Qt16,
    ushort* __restrict__ Cn16, ushort* __restrict__ Qn16,
    float* __restrict__ c1part, float* __restrict__ q2part,
    float* __restrict__ out) {
  __shared__ float tile[64][65];
  __shared__ float cred[64][4];
  int b = blockIdx.y;
  int tid = blockIdx.x;
  int t = threadIdx.x, c = t & 63, r0 = t >> 6;
  if (tid < 32) {
    int d0 = (tid >> 4) * 64, l0 = (tid & 15) * 64;
    const float* src = C + (size_t)b * ND * NLC;
    float* o0 = out + (size_t)b * 4 * ND * NLC;
    float part = 0.f;
#pragma unroll
    for (int p = 0; p < 16; ++p) {
      int r = r0 + p * 4;
      float v = src[(size_t)(d0 + r) * NLC + l0 + c];
      tile[c][r] = v * w[2 * ND + d0 + r];
      part += v * w[d0 + r];
      o0[(size_t)(d0 + r) * NLC + l0 + c] = v;   // channel 0 = C copy
    }
    cred[c][r0] = part;
    __syncthreads();
    ushort* dst = Ctw3 + (size_t)b * NLC * ND;
#pragma unroll
    for (int p = 0; p < 16; ++p) {
      int r = r0 + p * 4;
      dst[(size_t)(l0 + r) * ND + d0 + c] = f2bf(tile[r][c]);
    }
    if (t < 64)
      c1part[(size_t)(tid >> 4) * NB * NLC + b * NLC + l0 + t] =
          cred[t][0] + cred[t][1] + cred[t][2] + cred[t][3];
  } else if (tid < 40) {
    int q = tid - 32;
    int d0 = (q >> 2) * 64, m0 = (q & 3) * 64;
    const float* src = Q + (size_t)b * ND * NLQ;
    float part = 0.f;
#pragma unroll
    for (int p = 0; p < 16; ++p) {
      int r = r0 + p * 4;
      float v = src[(size_t)(d0 + r) * NLQ + m0 + c];
      tile[c][r] = v;
      part += v * w[ND + d0 + r];
    }
    cred[c][r0] = part;
    __syncthreads();
    ushort* dst = Qt16 + (size_t)b * NLQ * ND;
#pragma unroll
    for (int p = 0; p < 16; ++p) {
      int r = r0 + p * 4;
      dst[(size_t)(m0 + r) * ND + d0 + c] = f2bf(tile[r][c]);
    }
    if (t < 64)
      q2part[(size_t)(q >> 2) * NB * NLQ + b * NLQ + m0 + t] =
          cred[t][0] + cred[t][1] + cred[t][2] + cred[t][3];
  } else if (tid < 56) {
    size_t ofs = (size_t)(tid - 40) * 8192;
    const float* src = C + (size_t)b * ND * NLC + ofs;
    ushort* dst = Cn16 + (size_t)b * ND * NLC + ofs;
#pragma unroll
    for (int it = 0; it < 4; ++it) {
      int e = (it * 256 + t) * 8;
      float4 v0 = *(const float4*)(src + e), v1 = *(const float4*)(src + e + 4);
      *(uint4*)(dst + e) = pack8(v0.x, v0.y, v0.z, v0.w, v1.x, v1.y, v1.z, v1.w);
    }
  } else {
    size_t ofs = (size_t)(tid - 56) * 16384;
    const float* src = Q + (size_t)b * ND * NLQ + ofs;
    ushort* dst = Qn16 + (size_t)b * ND * NLQ + ofs;
#pragma unroll
    for (int it = 0; it < 8; ++it) {
      int e = (it * 256 + t) * 8;
      float4 v0 = *(const float4*)(src + e), v1 = *(const float4*)(src + e + 4);
      *(uint4*)(dst + e) = pack8(v0.x, v0.y, v0.z, v0.w, v1.x, v1.y, v1.z, v1.w);
    }
  }
}

// -------------------------------------------------------------------------
// Fused: S-tile (128 l x 256 m, K=128 MFMA) + biases; row max/sum; e1=bf16
// exp(S+qneg-rmax); column partial sums; e1g store ([l][m]); e1t store
// ([m][l] = e1 * rowfac, per-chunk normalized). No T GEMM here (see tmat).
__global__ __launch_bounds__(512, 4) void score_stats(
    const ushort* __restrict__ Ctw3, const ushort* __restrict__ Qt16,
    const float* __restrict__ c1part, const float* __restrict__ q2part,
    const float* __restrict__ cmask, const float* __restrict__ qmask,
    ushort* __restrict__ e1g, ushort* __restrict__ e1t,
    float* __restrict__ rscale_g, float* __restrict__ psum_part,
    float* __restrict__ chunkmax_g) {
  __shared__ union {
    struct { __align__(16) ushort As[128 * 32]; __align__(16) ushort Bs[256 * 32]; } s;
    struct { float rowred[128][4]; float rowsum[128][4]; float colred[256][2]; } red;
    __align__(16) ushort bounce[128 * 264];
    __align__(16) ushort bounce2[256 * 136];
  } u;
  __shared__ float rmaxs[128];
  __shared__ float rcs[128];   // rmax+cneg, then rowfac
  __shared__ float cnegs[128];
  __shared__ float qnegs[256];
  __shared__ float c1s[128];
  __shared__ float q2s[256];
  __shared__ float chunkmax_s;

  int b = blockIdx.y, chunk = blockIdx.x, l0 = chunk * 128;
  int t = threadIdx.x, lane = t & 63, wid = t >> 6;
  int wy = wid >> 2, wx = wid & 3, ln = lane & 15, qd = lane >> 4;

  if (t < 128) {
    int idx = b * NLC + l0 + t;
    c1s[t] = c1part[idx] + c1part[NB * NLC + idx];
    cnegs[t] = (1.f - cmask[idx]) * FNEG;
  } else if (t < 384) {
    int m = t - 128;
    int idx = b * NLQ + m;
    q2s[m] = q2part[idx] + q2part[NB * NLQ + idx];
    qnegs[m] = (1.f - qmask[idx]) * FNEG;
  }

  const ushort* Ab = Ctw3 + (size_t)b * NLC * ND;
  const ushort* Bb = Qt16 + (size_t)b * NLQ * ND;
  f32x4 acc[4][4];
#pragma unroll
  for (int i = 0; i < 4; ++i)
#pragma unroll
    for (int j = 0; j < 4; ++j) acc[i][j] = (f32x4){0.f, 0.f, 0.f, 0.f};

  for (int kk = 0; kk < ND; kk += 32) {
#pragma unroll
    for (int p = 0; p < 3; ++p) {
      int e4 = p * 512 + t;
      if (e4 < 512) {
        int r = e4 >> 2, cc = (e4 & 3) * 8;
        *(int4*)(u.s.As + r * 32 + cc) = *(const int4*)(Ab + (size_t)(l0 + r) * ND + kk + cc);
      } else {
        int e = e4 - 512;
        int r = e >> 2, cc = (e & 3) * 8;
        *(int4*)(u.s.Bs + r * 32 + cc) = *(const int4*)(Bb + (size_t)r * ND + kk + cc);
      }
    }
    __syncthreads();
    bf16x8 af[4], bfr[4];
#pragma unroll
    for (int i = 0; i < 4; ++i) {
      af[i]  = ldfrag(u.s.As + (wy * 64 + i * 16 + ln) * 32 + qd * 8);
      bfr[i] = ldfrag(u.s.Bs + (wx * 64 + i * 16 + ln) * 32 + qd * 8);
    }
#pragma unroll
    for (int i = 0; i < 4; ++i)
#pragma unroll
      for (int j = 0; j < 4; ++j)
        acc[i][j] = __builtin_amdgcn_mfma_f32_16x16x32_bf16(af[i], bfr[j], acc[i][j], 0, 0, 0);
    __syncthreads();
  }

  // add biases; qneg per column
  float qnj[4], q2j[4];
#pragma unroll
  for (int j = 0; j < 4; ++j) {
    int m = wx * 64 + j * 16 + ln;
    qnj[j] = qnegs[m];
    q2j[j] = q2s[m];
  }
#pragma unroll
  for (int i = 0; i < 4; ++i)
#pragma unroll
    for (int r = 0; r < 4; ++r) {
      int ll = wy * 64 + i * 16 + qd * 4 + r;
      float cv = c1s[ll];
#pragma unroll
      for (int j = 0; j < 4; ++j) acc[i][j][r] += cv + q2j[j];
    }

  // row max over m
#pragma unroll
  for (int i = 0; i < 4; ++i)
#pragma unroll
    for (int r = 0; r < 4; ++r) {
      float v = -INFINITY;
#pragma unroll
      for (int j = 0; j < 4; ++j) v = fmaxf(v, acc[i][j][r] + qnj[j]);
      v = fmaxf(v, __shfl_xor(v, 1));
      v = fmaxf(v, __shfl_xor(v, 2));
      v = fmaxf(v, __shfl_xor(v, 4));
      v = fmaxf(v, __shfl_xor(v, 8));
      if (ln == 0) u.red.rowred[wy * 64 + i * 16 + qd * 4 + r][wx] = v;
    }
  __syncthreads();
  if (t < 128) {
    float v = fmaxf(fmaxf(u.red.rowred[t][0], u.red.rowred[t][1]),
                    fmaxf(u.red.rowred[t][2], u.red.rowred[t][3]));
    rmaxs[t] = v;
    rcs[t] = v + cnegs[t];
  }
  __syncthreads();
  if (t < 64) {
    float v = fmaxf(rcs[t], rcs[t + 64]);
    v = fmaxf(v, __shfl_xor(v, 1));
    v = fmaxf(v, __shfl_xor(v, 2));
    v = fmaxf(v, __shfl_xor(v, 4));
    v = fmaxf(v, __shfl_xor(v, 8));
    v = fmaxf(v, __shfl_xor(v, 16));
    v = fmaxf(v, __shfl_xor(v, 32));
    if (t == 0) chunkmax_s = v;
  }
  __syncthreads();
  if (t < 128) rcs[t] = __expf(rcs[t] - chunkmax_s);  // rowfac
  __syncthreads();

  // e1 (overwrite acc), row sums, column partial sums
  float cs[4] = {0.f, 0.f, 0.f, 0.f};
#pragma unroll
  for (int i = 0; i < 4; ++i)
#pragma unroll
    for (int r = 0; r < 4; ++r) {
      int ll = wy * 64 + i * 16 + qd * 4 + r;
      float rmx = rmaxs[ll], rf = rcs[ll];
      float rs = 0.f;
#pragma unroll
      for (int j = 0; j < 4; ++j) {
        float e = __expf(acc[i][j][r] + qnj[j] - rmx);
        acc[i][j][r] = e;
        rs += e;
        cs[j] += e * rf;
      }
      rs += __shfl_xor(rs, 1);
      rs += __shfl_xor(rs, 2);
      rs += __shfl_xor(rs, 4);
      rs += __shfl_xor(rs, 8);
      if (ln == 0) u.red.rowsum[ll][wx] = rs;
    }
#pragma unroll
  for (int j = 0; j < 4; ++j) {
    float v = cs[j];
    v += __shfl_xor(v, 16);
    v += __shfl_xor(v, 32);
    if (qd == 0) u.red.colred[wx * 64 + j * 16 + ln][wy] = v;
  }
  __syncthreads();
  if (t < 128)
    rscale_g[b * NLC + l0 + t] = 1.f / (u.red.rowsum[t][0] + u.red.rowsum[t][1] +
                                        u.red.rowsum[t][2] + u.red.rowsum[t][3]);
  if (t >= 256 && t < 512) {
    int m = t - 256;
    psum_part[(b * 8 + chunk) * NLQ + m] = u.red.colred[m][0] + u.red.colred[m][1];
  }
  if (t == 0) chunkmax_g[b * 8 + chunk] = chunkmax_s;
  __syncthreads();  // red reads done before bounce writes

  // pass 1: bounce e1 through LDS for coalesced bf16 stores ([l][m])
#pragma unroll
  for (int i = 0; i < 4; ++i)
#pragma unroll
    for (int r = 0; r < 4; ++r) {
      int ll = wy * 64 + i * 16 + qd * 4 + r;
#pragma unroll
      for (int j = 0; j < 4; ++j)
        u.bounce[ll * 264 + wx * 64 + j * 16 + ln] = f2bf(acc[i][j][r]);
    }
  __syncthreads();
  ushort* Eb = e1g + (size_t)b * NLC * NLQ;
#pragma unroll
  for (int p = 0; p < 8; ++p) {
    int idx4 = p * 512 + t;
    int r = idx4 >> 5, c = (idx4 & 31) * 8;
    *(int4*)(Eb + (size_t)(l0 + r) * NLQ + c) = *(const int4*)(u.bounce + r * 264 + c);
  }
  __syncthreads();

  // pass 2: transposed column-path copy e1t[m][l] = e1 * rowfac
#pragma unroll
  for (int i = 0; i < 4; ++i)
#pragma unroll
    for (int r = 0; r < 4; ++r) {
      int ll = wy * 64 + i * 16 + qd * 4 + r;
      float rf = rcs[ll];
#pragma unroll
      for (int j = 0; j < 4; ++j)
        u.bounce2[(wx * 64 + j * 16 + ln) * 136 + ll] = f2bf(acc[i][j][r] * rf);
    }
  __syncthreads();
  ushort* Etb = e1t + (size_t)b * NLQ * NLC;
#pragma unroll
  for (int p = 0; p < 8; ++p) {
    int idx4 = p * 512 + t;
    int m = idx4 >> 4, l8 = idx4 & 15;
    *(int4*)(Etb + (size_t)m * NLC + l0 + l8 * 8) =
        *(const int4*)(u.bounce2 + m * 136 + l8 * 8);
  }
}

// -------------------------------------------------------------------------
__global__ __launch_bounds__(256) void stat_combine(
    const float* __restrict__ psum_part, const float* __restrict__ chunkmax_g,
    float* __restrict__ cinv) {
  __shared__ float cm[8];
  int b = blockIdx.x, t = threadIdx.x;
  if (t < 8) cm[t] = chunkmax_g[b * 8 + t];
  __syncthreads();
  float K = cm[0];
#pragma unroll
  for (int c = 1; c < 8; ++c) K = fmaxf(K, cm[c]);
  float s = 0.f;
#pragma unroll
  for (int c = 0; c < 8; ++c)
    s += psum_part[(b * 8 + c) * NLQ + t] * __expf(cm[c] - K);
  cinv[b * NLQ + t] = 1.f / s;
}

// -------------------------------------------------------------------------
// Tpart[b][ks][d][m] (bf16) = sum_{l in ks} Cn16[d][l] * e1t[m][l], the ks
// block's two chunks merged online in ascending-chunkmax order, normalized
// to M_ks = max(cm0, cm1). Both operands K-contiguous, int4-staged.
__global__ __launch_bounds__(512) void tmat_mfma(
    const ushort* __restrict__ Cn16, const ushort* __restrict__ e1t,
    const float* __restrict__ chunkmax_g, ushort* __restrict__ Tpart) {
  __shared__ __align__(16) ushort As[128 * 32];
  __shared__ __align__(16) ushort Bs[256 * 32];
  int b = blockIdx.y, ks = blockIdx.x;
  int t = threadIdx.x, lane = t & 63, wid = t >> 6;
  int wy = wid >> 2, wx = wid & 3, ln = lane & 15, qd = lane >> 4;
  const ushort* Cb = Cn16 + (size_t)b * ND * NLC;
  const ushort* Eb = e1t + (size_t)b * NLQ * NLC;
  float cm0 = chunkmax_g[b * 8 + 2 * ks];
  float cm1 = chunkmax_g[b * 8 + 2 * ks + 1];
  int first = (cm0 <= cm1) ? 0 : 1;
  float resc = __expf(fminf(cm0, cm1) - fmaxf(cm0, cm1));
  f32x4 acc[4][4];
#pragma unroll
  for (int i = 0; i < 4; ++i)
#pragma unroll
    for (int j = 0; j < 4; ++j) acc[i][j] = (f32x4){0.f, 0.f, 0.f, 0.f};

  for (int h = 0; h < 2; ++h) {
    int lbase = (2 * ks + (h ? 1 - first : first)) * 128;
    for (int c0 = 0; c0 < 128; c0 += 32) {
#pragma unroll
      for (int p = 0; p < 3; ++p) {
        int e4 = p * 512 + t;
        if (e4 < 512) {
          int r = e4 >> 2, cc = (e4 & 3) * 8;
          *(int4*)(As + r * 32 + cc) =
              *(const int4*)(Cb + (size_t)r * NLC + lbase + c0 + cc);
        } else {
          int e = e4 - 512;
          int rm = e >> 2, cc = (e & 3) * 8;
          *(int4*)(Bs + rm * 32 + cc) =
              *(const int4*)(Eb + (size_t)rm * NLC + lbase + c0 + cc);
        }
      }
      __syncthreads();
      bf16x8 af[4], bfr[4];
#pragma unroll
      for (int i = 0; i < 4; ++i) {
        af[i]  = ldfrag(As + (wy * 64 + i * 16 + ln) * 32 + qd * 8);
        bfr[i] = ldfrag(Bs + (wx * 64 + i * 16 + ln) * 32 + qd * 8);
      }
#pragma unroll
      for (int i = 0; i < 4; ++i)
#pragma unroll
        for (int j = 0; j < 4; ++j)
          acc[i][j] = __builtin_amdgcn_mfma_f32_16x16x32_bf16(af[i], bfr[j], acc[i][j], 0, 0, 0);
      __syncthreads();
    }
    if (h == 0) {
#pragma unroll
      for (int i = 0; i < 4; ++i)
#pragma unroll
        for (int j = 0; j < 4; ++j)
#pragma unroll
          for (int r = 0; r < 4; ++r) acc[i][j][r] *= resc;
    }
  }
  ushort* Tb = Tpart + ((size_t)(b * 4 + ks)) * ND * NLQ;
#pragma unroll
  for (int i = 0; i < 4; ++i)
#pragma unroll
    for (int r = 0; r < 4; ++r) {
      int d = wy * 64 + i * 16 + qd * 4 + r;
#pragma unroll
      for (int j = 0; j < 4; ++j) {
        int m = wx * 64 + j * 16 + ln;
        Tb[(size_t)d * NLQ + m] = f2bf(acc[i][j][r]);
      }
    }
}

// -------------------------------------------------------------------------
// Tt[d][m] = bf16( cinv[m] * sum_ks exp(M_ks - K) * Tpart[ks][d][m] )
__global__ __launch_bounds__(256) void tcombine(
    const ushort* __restrict__ Tpart, const float* __restrict__ cinv,
    const float* __restrict__ chunkmax_g, ushort* __restrict__ Tt) {
  int gid = blockIdx.x * 256 + threadIdx.x;
  int e = gid * 8;
  int b = e >> 15;
  int r = e & 32767;
  int m = r & 255;
  const float* cmb = chunkmax_g + b * 8;
  float K = cmb[0];
#pragma unroll
  for (int c = 1; c < 8; ++c) K = fmaxf(K, cmb[c]);
  float s[8] = {0.f, 0.f, 0.f, 0.f, 0.f, 0.f, 0.f, 0.f};
#pragma unroll
  for (int ks = 0; ks < 4; ++ks) {
    float fac = __expf(fmaxf(cmb[2 * ks], cmb[2 * ks + 1]) - K);
    int4 v = *(const int4*)(Tpart + ((size_t)(b * 4 + ks)) * ND * NLQ + r);
    const ushort* sv = (const ushort*)&v;
#pragma unroll
    for (int k = 0; k < 8; ++k) s[k] += fac * bf2f(sv[k]);
  }
  float4 ci0 = *(const float4*)(cinv + b * NLQ + m);
  float4 ci1 = *(const float4*)(cinv + b * NLQ + m + 4);
  *(uint4*)(Tt + (size_t)b * ND * NLQ + r) =
      pack8(s[0] * ci0.x, s[1] * ci0.y, s[2] * ci0.z, s[3] * ci0.w,
            s[4] * ci1.x, s[5] * ci1.y, s[6] * ci1.z, s[7] * ci1.w);
}

// -------------------------------------------------------------------------
// A[d][l] = sum_m Qn16[d][m]*e1[l][m]; Bv[d][l] = sum_m Tt[d][m]*e1[l][m];
// 512 threads / 8 waves: wave = (wy d-half 64) x (wx l-quarter 32).
// LDS-bounce epilogue -> coalesced float4 writes of {A, C*A, C*Bv}.
__global__ __launch_bounds__(512, 4) void outk(
    const float* __restrict__ C, const ushort* __restrict__ Qn16,
    const ushort* __restrict__ Tt, const ushort* __restrict__ e1g,
    const float* __restrict__ rscale, float* __restrict__ out) {
  __shared__ union {
    struct { __align__(16) ushort As1[128 * 32]; __align__(16) ushort As2[128 * 32];
             __align__(16) ushort Bs[128 * 32]; } st;
    struct { float a[32][132]; float bv[32][132]; } ep;
  } u;
  int b = blockIdx.y;
  int l0 = blockIdx.x * 128;
  const ushort* Qb = Qn16 + (size_t)b * ND * NLQ;
  const ushort* Tb = Tt + (size_t)b * ND * NLQ;
  const ushort* Eb = e1g + (size_t)b * NLC * NLQ;
  int t = threadIdx.x, lane = t & 63, wid = t >> 6;
  int wy = wid >> 2, wx = wid & 3;       // wy: d-half, wx: l-quarter
  int ln = lane & 15, qd = lane >> 4;
  f32x4 acc1[4][2], acc2[4][2];
#pragma unroll
  for (int i = 0; i < 4; ++i)
#pragma unroll
    for (int j = 0; j < 2; ++j) {
      acc1[i][j] = (f32x4){0.f, 0.f, 0.f, 0.f};
      acc2[i][j] = (f32x4){0.f, 0.f, 0.f, 0.f};
    }

  for (int m0 = 0; m0 < NLQ; m0 += 32) {
    {
      int r = t >> 2, cc = (t & 3) * 8;
      *(int4*)(u.st.As1 + r * 32 + cc) = *(const int4*)(Qb + (size_t)r * NLQ + m0 + cc);
      *(int4*)(u.st.As2 + r * 32 + cc) = *(const int4*)(Tb + (size_t)r * NLQ + m0 + cc);
      *(int4*)(u.st.Bs + r * 32 + cc)  = *(const int4*)(Eb + (size_t)(l0 + r) * NLQ + m0 + cc);
    }
    __syncthreads();
    bf16x8 a1[4], a2[4], bfr[2];
#pragma unroll
    for (int i = 0; i < 4; ++i) {
      a1[i] = ldfrag(u.st.As1 + (wy * 64 + i * 16 + ln) * 32 + qd * 8);
      a2[i] = ldfrag(u.st.As2 + (wy * 64 + i * 16 + ln) * 32 + qd * 8);
    }
#pragma unroll
    for (int j = 0; j < 2; ++j)
      bfr[j] = ldfrag(u.st.Bs + (wx * 32 + j * 16 + ln) * 32 + qd * 8);
#pragma unroll
    for (int i = 0; i < 4; ++i)
#pragma unroll
      for (int j = 0; j < 2; ++j) {
        acc1[i][j] = __builtin_amdgcn_mfma_f32_16x16x32_bf16(a1[i], bfr[j], acc1[i][j], 0, 0, 0);
        acc2[i][j] = __builtin_amdgcn_mfma_f32_16x16x32_bf16(a2[i], bfr[j], acc2[i][j], 0, 0, 0);
      }
    __syncthreads();
  }

  // rscale per fragment column
  float rsj[2];
#pragma unroll
  for (int j = 0; j < 2; ++j)
    rsj[j] = rscale[b * NLC + l0 + wx * 32 + j * 16 + ln];

  const float* Cbase = C + (size_t)b * ND * NLC;
  float* outb = out + (size_t)b * 4 * ND * NLC;
#pragma unroll
  for (int db = 0; db < 4; ++db) {
    __syncthreads();  // previous pass's LDS reads / staging reads done
    if (wy == (db >> 1)) {
      int ibase = (db & 1) * 2;
#pragma unroll
      for (int ii = 0; ii < 2; ++ii) {
        int i = ibase + ii;
#pragma unroll
        for (int j = 0; j < 2; ++j) {
          int lc = wx * 32 + j * 16 + ln;
#pragma unroll
          for (int r = 0; r < 4; ++r) {
            int dr = ii * 16 + qd * 4 + r;
            u.ep.a[dr][lc]  = acc1[i][j][r] * rsj[j];
            u.ep.bv[dr][lc] = acc2[i][j][r] * rsj[j];
          }
        }
      }
    }
    __syncthreads();
    // coalesced write pass: 32 rows x 128 cols, 16 threads/row x 8 floats
    int row = t >> 4, colf = (t & 15) * 8;
    int d = db * 32 + row;
    const float* Crow = Cbase + (size_t)d * NLC + l0 + colf;
    float4 c0 = *(const float4*)(Crow), c1 = *(const float4*)(Crow + 4);
    float4 a0 = *(const float4*)&u.ep.a[row][colf];
    float4 a1v = *(const float4*)&u.ep.a[row][colf + 4];
    float4 b0 = *(const float4*)&u.ep.bv[row][colf];
    float4 b1 = *(const float4*)&u.ep.bv[row][colf + 4];
    float* oA = outb + (size_t)(128 + d) * NLC + l0 + colf;
    float* oCA = outb + (size_t)(256 + d) * NLC + l0 + colf;
    float* oCB = outb + (size_t)(384 + d) * NLC + l0 + colf;
    *(float4*)(oA) = a0;
    *(float4*)(oA + 4) = a1v;
    *(float4*)(oCA) = (float4){c0.x * a0.x, c0.y * a0.y, c0.z * a0.z, c0.w * a0.w};
    *(float4*)(oCA + 4) = (float4){c1.x * a1v.x, c1.y * a1v.y, c1.z * a1v.z, c1.w * a1v.w};
    *(float4*)(oCB) = (float4){c0.x * b0.x, c0.y * b0.y, c0.z * b0.z, c0.w * b0.w};
    *(float4*)(oCB + 4) = (float4){c1.x * b1.x, c1.y * b1.y, c1.z * b1.z, c1.w * b1.w};
  }
}

// -------------------------------------------------------------------------
extern "C" void kernel_launch(void* const* d_in, const int* in_sizes, int n_in,
                              void* d_out, int out_size, void* d_ws, size_t ws_size,
                              hipStream_t stream) {
  const float* C     = (const float*)d_in[0];
  const float* Q     = (const float*)d_in[1];
  const float* cmask = (const float*)d_in[2];
  const float* qmask = (const float*)d_in[3];
  const float* w     = (const float*)d_in[4];
  float* out = (float*)d_out;

  char* p = (char*)d_ws;
  auto alloc = [&](size_t bytes) { char* r = p; p += (bytes + 255) & ~(size_t)255; return r; };
  ushort* e1g    = (ushort*)alloc((size_t)NB * NLC * NLQ * 2);
  ushort* e1t    = (ushort*)alloc((size_t)NB * NLQ * NLC * 2);
  ushort* Ctw3   = (ushort*)alloc((size_t)NB * NLC * ND * 2);
  ushort* Qt16   = (ushort*)alloc((size_t)NB * NLQ * ND * 2);
  ushort* Cn16   = (ushort*)alloc((size_t)NB * ND * NLC * 2);
  ushort* Qn16   = (ushort*)alloc((size_t)NB * ND * NLQ * 2);
  ushort* Tpart  = (ushort*)alloc((size_t)NB * 4 * ND * NLQ * 2);
  ushort* Tt     = (ushort*)alloc((size_t)NB * ND * NLQ * 2);
  float*  c1part = (float*)alloc((size_t)2 * NB * NLC * 4);
  float*  q2part = (float*)alloc((size_t)2 * NB * NLQ * 4);
  float*  rscale = (float*)alloc((size_t)NB * NLC * 4);
  float*  cinv   = (float*)alloc((size_t)NB * NLQ * 4);
  float*  psum   = (float*)alloc((size_t)NB * 8 * NLQ * 4);
  float*  chmax  = (float*)alloc((size_t)NB * 8 * 4);

  convert_kernel<<<dim3(58, NB), 256, 0, stream>>>(C, Q, w, Ctw3, Qt16, Cn16, Qn16,
                                                   c1part, q2part, out);
  score_stats<<<dim3(NLC / 128, NB), 512, 0, stream>>>(
      Ctw3, Qt16, c1part, q2part, cmask, qmask, e1g, e1t, rscale, psum, chmax);
  stat_combine<<<NB, 256, 0, stream>>>(psum, chmax, cinv);
  tmat_mfma<<<dim3(4, NB), 512, 0, stream>>>(Cn16, e1t, chmax, Tpart);
  tcombine<<<(NB * ND * NLQ / 8) / 256, 256, 0, stream>>>(Tpart, cinv, chmax, Tt);
  outk<<<dim3(NLC / 128, NB), 512, 0, stream>>>(C, Qn16, Tt, e1g, rscale, out);
}